// Round 2
// baseline (1782.796 us; speedup 1.0000x reference)
//
#include <hip/hip_runtime.h>

#define NB 4
#define NN 4096
#define NC 64
#define KNB 16
#define NS 1024
#define M1TOT (NB*NN*KNB)   // 262144
#define EPSBN 1e-5f
#define XROW 68

// ---- module-scope scratch (avoids any ws_size assumption; fully rewritten every call)
__device__ __align__(16) int   g_nbr[NB*NN*KNB];
__device__ int   g_cslot[NB*NN];
__device__ float g_sum1[128];
__device__ float g_sq1[128];
__device__ float g_sum2[128];
__device__ float g_sq2[128];
__device__ __align__(16) float g_hmin[NB*NS*128];
__device__ __align__(16) float g_hmax[NB*NS*128];

// ================= kA: blocks 0-3 FPS, blocks 4-67 KNN, block 68 stat-zero =================
__global__ __launch_bounds__(256) void kA(const float* __restrict__ pos, float* __restrict__ out)
{
    __shared__ float spx[NN], spy[NN], spz[NN];
    __shared__ float sbv[2][4];
    __shared__ int   sbj[2][4];
    __shared__ int   cnts[256];
    const int blk = blockIdx.x, t = threadIdx.x;

    if (blk >= 68) {
        if (t < 128) { g_sum1[t]=0.f; g_sq1[t]=0.f; g_sum2[t]=0.f; g_sq2[t]=0.f; }
        return;
    }

    if (blk < 4) {
        // ---------------- Farthest Point Sampling, batch = blk ----------------
        const int b = blk;
        const float* pb = pos + (size_t)b*NN*3;
        for (int i = t; i < NN; i += 256) { spx[i]=pb[3*i]; spy[i]=pb[3*i+1]; spz[i]=pb[3*i+2]; }
        __syncthreads();
        float rx[16], ry[16], rz[16], rd[16];
        #pragma unroll
        for (int i=0;i<16;i++){ int j=(t<<4)+i; rx[i]=spx[j]; ry[i]=spy[j]; rz[i]=spz[j]; rd[i]=1e10f; }
        unsigned sel = (t==0) ? 1u : 0u;           // node 0 is always selected
        float cx = spx[0], cy = spy[0], cz = spz[0];
        const int lane = t & 63, wid = t >> 6;

        for (int it = 0; it < NS-1; ++it) {
            const int par = it & 1;
            float bv = -1.f; int bj = 0;
            #pragma unroll
            for (int i=0;i<16;i++){
                float dx = rx[i]-cx, dy = ry[i]-cy, dz = rz[i]-cz;
                // exact reference formula: (dx*dx + dy*dy) + dz*dz, no FMA contraction
                float d = __fadd_rn(__fadd_rn(__fmul_rn(dx,dx),__fmul_rn(dy,dy)),__fmul_rn(dz,dz));
                float nd = fminf(rd[i], d);
                rd[i] = nd;
                if (nd > bv) { bv = nd; bj = (t<<4)+i; }    // strict > keeps lowest index
            }
            // wave argmax (value desc, index asc)
            #pragma unroll
            for (int m=1;m<64;m<<=1){
                float ov = __shfl_xor(bv, m);
                int   oj = __shfl_xor(bj, m);
                if (ov > bv || (ov == bv && oj < bj)) { bv = ov; bj = oj; }
            }
            if (lane == 0) { sbv[par][wid] = bv; sbj[par][wid] = bj; }
            __syncthreads();    // single barrier/iter; slots are parity double-buffered
            float v2 = sbv[par][lane & 3];
            int   j2 = sbj[par][lane & 3];
            #pragma unroll
            for (int m=1;m<4;m<<=1){
                float ov = __shfl_xor(v2, m);
                int   oj = __shfl_xor(j2, m);
                if (ov > v2 || (ov == v2 && oj < j2)) { v2 = ov; j2 = oj; }
            }
            cx = spx[j2]; cy = spy[j2]; cz = spz[j2];
            unsigned rel = (unsigned)(j2 - (t<<4));
            if (rel < 16u) sel |= (1u << rel);
        }
        // ordered compaction (ascending node index == reference's sorted centroids)
        cnts[t] = (int)__popc(sel);
        __syncthreads();
        if (t == 0) { int run = 0; for (int i=0;i<256;i++){ int c = cnts[i]; cnts[i] = run; run += c; } }
        __syncthreads();
        int base = cnts[t];
        #pragma unroll
        for (int i=0;i<16;i++){
            int j = (t<<4)+i;
            if (sel & (1u<<i)) {
                g_cslot[b*NN + j] = base;
                float* po = out + (size_t)((b<<10) + base)*3;
                po[0]=rx[i]; po[1]=ry[i]; po[2]=rz[i];
                base++;
            } else {
                g_cslot[b*NN + j] = -1;
            }
        }
    } else {
        // ---------------- exact 16-NN, one query per thread ----------------
        const int kb = blk - 4;
        const int b = kb >> 4;                    // 16 blocks per batch
        const int q = ((kb & 15) << 8) + t;
        const float* pb = pos + (size_t)b*NN*3;
        for (int i = t; i < NN; i += 256) { spx[i]=pb[3*i]; spy[i]=pb[3*i+1]; spz[i]=pb[3*i+2]; }
        __syncthreads();
        const float qx = spx[q], qy = spy[q], qz = spz[q];
        float bd[16]; int bi[16];
        #pragma unroll
        for (int u=0;u<16;u++){ bd[u]=3e38f; bi[u]=0; }
        float wmax = 3e38f;
        for (int j = 0; j < NN; ++j) {
            float dx = spx[j]-qx, dy = spy[j]-qy, dz = spz[j]-qz;
            float d = __fadd_rn(__fadd_rn(__fmul_rn(dx,dx),__fmul_rn(dy,dy)),__fmul_rn(dz,dz));
            if (d < wmax) {                        // strict <: lowest index wins boundary ties
                float m0 = bd[0]; int mj = 0;
                #pragma unroll
                for (int u=1;u<16;u++){ if (bd[u] > m0) { m0 = bd[u]; mj = u; } }
                #pragma unroll
                for (int u=0;u<16;u++){ if (u == mj) { bd[u] = d; bi[u] = j; } }
                wmax = bd[0];
                #pragma unroll
                for (int u=1;u<16;u++) wmax = fmaxf(wmax, bd[u]);
            }
        }
        int* dst = g_nbr + ((size_t)(b*NN + q) << 4);
        #pragma unroll
        for (int u=0;u<16;u++) dst[u] = bi[u];
    }
}

// ============ shared layer-1 stage+GEMM: 64 samples (4 nodes x 16 nbrs) x 128 ch ============
// thread t: cg = t&15 -> channels 8cg..8cg+7 ; sg = t>>4 -> samples sg+16r (r=0..3)
__device__ __forceinline__ void stage_gemm1(const float* __restrict__ feat, const float* __restrict__ pos,
                                            const float* __restrict__ W1,
                                            float* __restrict__ xls, float* __restrict__ wls,
                                            int b, int nb, int t, float acc[4][8])
{
    // W1 [128][67] -> wls[row][co], row permuted so x layout is feat(0..63), rel(64..66)
    for (int i = t; i < 128*67; i += 256) {
        int co = i / 67, ci = i - co*67;
        int row = (ci < 3) ? (64 + ci) : (ci - 3);
        wls[row*128 + co] = W1[i];
    }
    {
        const int s = t >> 2, h = t & 3;
        const int n = nb + (s >> 4), k = s & 15;
        const int gq = b*NN + n;
        const int idx = g_nbr[(gq << 4) + k];
        const float* fr = feat + ((size_t)(b*NN + idx) << 6) + (h << 4);
        float* xr = xls + s*XROW + (h << 4);
        #pragma unroll
        for (int u=0;u<4;u++) ((float4*)xr)[u] = ((const float4*)fr)[u];
        if (h == 0) {
            const float* pn = pos + (size_t)gq*3;
            const float* pi = pos + (size_t)(b*NN + idx)*3;
            xls[s*XROW + 64] = pi[0]-pn[0];
            xls[s*XROW + 65] = pi[1]-pn[1];
            xls[s*XROW + 66] = pi[2]-pn[2];
        }
    }
    __syncthreads();
    const int cg = t & 15, sg = t >> 4;
    #pragma unroll
    for (int r=0;r<4;r++)
        #pragma unroll
        for (int c=0;c<8;c++) acc[r][c] = 0.f;
    for (int i = 0; i < 67; ++i) {
        float4 wa = *(const float4*)&wls[i*128 + (cg<<3)];
        float4 wb = *(const float4*)&wls[i*128 + (cg<<3) + 4];
        #pragma unroll
        for (int r=0;r<4;r++){
            float xv = xls[(sg + (r<<4))*XROW + i];
            acc[r][0] = fmaf(xv, wa.x, acc[r][0]);
            acc[r][1] = fmaf(xv, wa.y, acc[r][1]);
            acc[r][2] = fmaf(xv, wa.z, acc[r][2]);
            acc[r][3] = fmaf(xv, wa.w, acc[r][3]);
            acc[r][4] = fmaf(xv, wb.x, acc[r][4]);
            acc[r][5] = fmaf(xv, wb.y, acc[r][5]);
            acc[r][6] = fmaf(xv, wb.z, acc[r][6]);
            acc[r][7] = fmaf(xv, wb.w, acc[r][7]);
        }
    }
}

// ================= kStats1: layer-1 pre-activation stats (sum, sumsq per channel) =================
__global__ __launch_bounds__(256) void kStats1(const float* __restrict__ feat, const float* __restrict__ pos,
                                               const float* __restrict__ W1, const float* __restrict__ b1)
{
    __shared__ __align__(16) float xls[64*XROW];
    __shared__ __align__(16) float wls[67*128];
    __shared__ float redS4[512], redQ4[512];
    const int t = threadIdx.x, blk = blockIdx.x;
    const int b = blk >> 10, nb = (blk & 1023) << 2;
    float acc[4][8];
    stage_gemm1(feat, pos, W1, xls, wls, b, nb, t, acc);
    const int cg = t & 15, sg = t >> 4, w = sg >> 2;
    #pragma unroll
    for (int c=0;c<8;c++){
        const int ch = (cg<<3)+c;
        const float bb = b1[ch];
        float ls=0.f, lq=0.f;
        #pragma unroll
        for (int r=0;r<4;r++){ float h1 = acc[r][c] + bb; ls += h1; lq = fmaf(h1,h1,lq); }
        ls += __shfl_xor(ls,16); ls += __shfl_xor(ls,32);
        lq += __shfl_xor(lq,16); lq += __shfl_xor(lq,32);
        if ((sg & 3) == 0) { redS4[w*128 + ch] = ls; redQ4[w*128 + ch] = lq; }
    }
    __syncthreads();
    if (t < 128) {
        float s = redS4[t] + redS4[128+t] + redS4[256+t] + redS4[384+t];
        float q = redQ4[t] + redQ4[128+t] + redQ4[256+t] + redQ4[384+t];
        atomicAdd(&g_sum1[t], s);
        atomicAdd(&g_sq1[t], q);
    }
}

// ==== kPassB: recompute h1, BN1+ReLU -> y (LDS), layer-2 GEMM, BN2 stats, per-node min/max ====
__global__ __launch_bounds__(256) void kPassB(const float* __restrict__ feat, const float* __restrict__ pos,
        const float* __restrict__ W1, const float* __restrict__ b1,
        const float* __restrict__ gamma1, const float* __restrict__ beta1,
        const float* __restrict__ W2, const float* __restrict__ b2)
{
    // SB phase1: x[64*68]=4352 @0, W1t @4352 (8576) -> 12928
    // SB phase2: y[64*133]=8512 @0, W2 chunk [32*128]=4096 @8512
    __shared__ __align__(16) float SB[12928];
    __shared__ float scs[128], shs[128];
    __shared__ float redS4[512], redQ4[512];
    const int t = threadIdx.x, blk = blockIdx.x;
    const int b = blk >> 10, nb = (blk & 1023) << 2;
    if (t < 128) {
        const float inv = 1.f/(float)M1TOT;
        float mu  = g_sum1[t]*inv;
        float var = g_sq1[t]*inv - mu*mu;
        float sc  = gamma1[t]*rsqrtf(var + EPSBN);
        scs[t] = sc; shs[t] = beta1[t] - mu*sc;
    }
    float acc[4][8];
    stage_gemm1(feat, pos, W1, SB, SB + 64*XROW, b, nb, t, acc);
    const int cg = t & 15, sg = t >> 4, w = sg >> 2;
    __syncthreads();                       // all phase-1 LDS reads done before overwrite
    #pragma unroll
    for (int c=0;c<8;c++){
        const int ch = (cg<<3)+c;
        const float bb = b1[ch], sc = scs[ch], sh = shs[ch];
        #pragma unroll
        for (int r=0;r<4;r++){
            float yv = fmaxf(0.f, fmaf(acc[r][c] + bb, sc, sh));
            SB[(sg + (r<<4))*133 + ch] = yv;   // stride 133: conflict-free phase-2 reads
        }
    }
    __syncthreads();
    float acc2[4][8];
    #pragma unroll
    for (int r=0;r<4;r++)
        #pragma unroll
        for (int c=0;c<8;c++) acc2[r][c]=0.f;
    for (int kc = 0; kc < 4; ++kc) {
        for (int e = t; e < 4096; e += 256) {     // stage W2[:, kc*32 .. +32) transposed
            int dd = e >> 5, kk = e & 31;
            SB[8512 + kk*128 + dd] = W2[(dd << 7) + (kc<<5) + kk];
        }
        __syncthreads();
        for (int kk = 0; kk < 32; ++kk) {
            float4 wa = *(const float4*)&SB[8512 + (kk<<7) + (cg<<3)];
            float4 wb = *(const float4*)&SB[8512 + (kk<<7) + (cg<<3) + 4];
            const int kabs = (kc<<5) + kk;
            #pragma unroll
            for (int r=0;r<4;r++){
                float yv = SB[((sg<<2) + r)*133 + kabs];   // phase-2 samples: 4sg+r
                acc2[r][0] = fmaf(yv, wa.x, acc2[r][0]);
                acc2[r][1] = fmaf(yv, wa.y, acc2[r][1]);
                acc2[r][2] = fmaf(yv, wa.z, acc2[r][2]);
                acc2[r][3] = fmaf(yv, wa.w, acc2[r][3]);
                acc2[r][4] = fmaf(yv, wb.x, acc2[r][4]);
                acc2[r][5] = fmaf(yv, wb.y, acc2[r][5]);
                acc2[r][6] = fmaf(yv, wb.z, acc2[r][6]);
                acc2[r][7] = fmaf(yv, wb.w, acc2[r][7]);
            }
        }
        __syncthreads();
    }
    // epilogue: h2 = acc2 + b2 ; BN2 stats ; min/max over the 16 neighbors of each node
    #pragma unroll
    for (int c=0;c<8;c++){
        const int ch = (cg<<3)+c;
        const float bb = b2[ch];
        float ls=0.f, lq=0.f, mn=3e38f, mx=-3e38f;
        #pragma unroll
        for (int r=0;r<4;r++){
            float h2 = acc2[r][c] + bb;
            ls += h2; lq = fmaf(h2,h2,lq);
            mn = fminf(mn,h2); mx = fmaxf(mx,h2);
        }
        ls += __shfl_xor(ls,16); ls += __shfl_xor(ls,32);
        lq += __shfl_xor(lq,16); lq += __shfl_xor(lq,32);
        if ((sg & 3) == 0) { redS4[w*128 + ch] = ls; redQ4[w*128 + ch] = lq; }
        float o;
        o = __shfl_xor(mn,16); mn = fminf(mn,o);
        o = __shfl_xor(mn,32); mn = fminf(mn,o);
        o = __shfl_xor(mx,16); mx = fmaxf(mx,o);
        o = __shfl_xor(mx,32); mx = fmaxf(mx,o);
        if ((sg & 3) == 0) {
            const int node = nb + (sg >> 2);
            const int slot = g_cslot[b*NN + node];
            if (slot >= 0) {
                const int oo = (((b<<10)+slot)<<7) + ch;
                g_hmin[oo] = mn; g_hmax[oo] = mx;
            }
        }
    }
    __syncthreads();
    if (t < 128) {
        float s = redS4[t] + redS4[128+t] + redS4[256+t] + redS4[384+t];
        float q = redQ4[t] + redQ4[128+t] + redQ4[256+t] + redQ4[384+t];
        atomicAdd(&g_sum2[t], s);
        atomicAdd(&g_sq2[t], q);
    }
}

// ================= kFinal: BN2 affine + ReLU via min/max monotonicity, write feat_res =================
__global__ __launch_bounds__(256) void kFinal(const float* __restrict__ gamma2, const float* __restrict__ beta2,
                                              float* __restrict__ out)
{
    const int gid = blockIdx.x*256 + threadIdx.x;
    const int base = gid << 2;
    const int ch0 = base & 127;
    const float inv = 1.f/(float)M1TOT;
    float4 mx = *(const float4*)&g_hmax[base];
    float4 mn = *(const float4*)&g_hmin[base];
    float4 o;
    {
        float mu = g_sum2[ch0]*inv, var = g_sq2[ch0]*inv - mu*mu;
        float sc = gamma2[ch0]*rsqrtf(var+EPSBN), sh = beta2[ch0] - mu*sc;
        o.x = fmaxf(0.f, fmaf((sc >= 0.f) ? mx.x : mn.x, sc, sh));
    }
    {
        int ch = ch0+1;
        float mu = g_sum2[ch]*inv, var = g_sq2[ch]*inv - mu*mu;
        float sc = gamma2[ch]*rsqrtf(var+EPSBN), sh = beta2[ch] - mu*sc;
        o.y = fmaxf(0.f, fmaf((sc >= 0.f) ? mx.y : mn.y, sc, sh));
    }
    {
        int ch = ch0+2;
        float mu = g_sum2[ch]*inv, var = g_sq2[ch]*inv - mu*mu;
        float sc = gamma2[ch]*rsqrtf(var+EPSBN), sh = beta2[ch] - mu*sc;
        o.z = fmaxf(0.f, fmaf((sc >= 0.f) ? mx.z : mn.z, sc, sh));
    }
    {
        int ch = ch0+3;
        float mu = g_sum2[ch]*inv, var = g_sq2[ch]*inv - mu*mu;
        float sc = gamma2[ch]*rsqrtf(var+EPSBN), sh = beta2[ch] - mu*sc;
        o.w = fmaxf(0.f, fmaf((sc >= 0.f) ? mx.w : mn.w, sc, sh));
    }
    *(float4*)&out[12288 + base] = o;
}

extern "C" void kernel_launch(void* const* d_in, const int* in_sizes, int n_in,
                              void* d_out, int out_size, void* d_ws, size_t ws_size,
                              hipStream_t stream)
{
    (void)in_sizes; (void)n_in; (void)d_ws; (void)ws_size; (void)out_size;
    const float* feat = (const float*)d_in[0];
    const float* pos  = (const float*)d_in[1];
    const float* W1   = (const float*)d_in[2];
    const float* b1   = (const float*)d_in[3];
    const float* g1   = (const float*)d_in[4];
    const float* be1  = (const float*)d_in[5];
    const float* W2   = (const float*)d_in[6];
    const float* b2   = (const float*)d_in[7];
    const float* g2   = (const float*)d_in[8];
    const float* be2  = (const float*)d_in[9];
    float* out = (float*)d_out;

    kA<<<dim3(69),   dim3(256), 0, stream>>>(pos, out);
    kStats1<<<dim3(4096), dim3(256), 0, stream>>>(feat, pos, W1, b1);
    kPassB<<<dim3(4096),  dim3(256), 0, stream>>>(feat, pos, W1, b1, g1, be1, W2, b2);
    kFinal<<<dim3(512),   dim3(256), 0, stream>>>(g2, be2, out);
}